// Round 1
// baseline (17946.123 us; speedup 1.0000x reference)
//
#include <hip/hip_runtime.h>
#include <stdint.h>
#include <stddef.h>

// ---------------- problem constants ----------------
static constexpr int  T_STEPS   = 2048;
static constexpr int  BATCH     = 16;
static constexpr int  DIM       = 1024;
static constexpr long RROWS     = (long)T_STEPS * BATCH;   // 32768 rows of x
static constexpr long BD        = (long)BATCH * DIM;       // 16384
static constexpr long OUT_ELEMS = (long)T_STEPS * BD;      // 33554432

// ---------------- ws layout (bytes) ----------------
// wx   f32 [T][B][D]            128 MiB
// xbf  bf16[R][D]                64 MiB
// Whi  bf16[3072][1024]           6 MiB
// Wlo  bf16[3072][1024]           6 MiB
// hbh  bf16[2][B][D] (hi plane)  64 KiB
// hbl  bf16[2][B][D] (lo plane)  64 KiB
// flags int[64]
static constexpr size_t WX_OFF  = 0;
static constexpr size_t XBF_OFF = 134217728;
static constexpr size_t WHI_OFF = XBF_OFF + 67108864;   // 201326592
static constexpr size_t WLO_OFF = WHI_OFF + 6291456;    // 207618048
static constexpr size_t HBH_OFF = WLO_OFF + 6291456;    // 213909504
static constexpr size_t HBL_OFF = HBH_OFF + 65536;      // 213975040
static constexpr size_t FLG_OFF = HBL_OFF + 65536;      // 214040576

typedef __attribute__((ext_vector_type(4))) float          f32x4;
typedef __attribute__((ext_vector_type(8))) short          s16x8;
typedef __attribute__((ext_vector_type(4))) unsigned short u16x4;
typedef __attribute__((ext_vector_type(8))) unsigned short u16x8;

#define AS1 __attribute__((address_space(1)))
#define AS3 __attribute__((address_space(3)))

// ---------------- helpers ----------------
static __device__ __forceinline__ unsigned short f2bf(float x) {
  union { float f; unsigned u; } a; a.f = x;
  unsigned r = a.u + 0x7fffu + ((a.u >> 16) & 1u);
  return (unsigned short)(r >> 16);
}
static __device__ __forceinline__ float bf2f(unsigned short h) {
  union { unsigned u; float f; } a; a.u = ((unsigned)h) << 16; return a.f;
}
static __device__ __forceinline__ void gload_lds16(const void* g, void* l) {
  __builtin_amdgcn_global_load_lds((const AS1 void*)g, (AS3 void*)l, 16, 0, 0);
}

// ---------------- convert x -> bf16 ----------------
__global__ __launch_bounds__(256) void convert_x_kernel(const float* __restrict__ x,
                                                        unsigned short* __restrict__ xbf) {
  const long n8 = (RROWS * DIM) / 8;
  const long stride = (long)gridDim.x * blockDim.x;
  for (long i = (long)blockIdx.x * blockDim.x + threadIdx.x; i < n8; i += stride) {
    const float4* p = (const float4*)(x + i * 8);
    float4 v0 = p[0], v1 = p[1];
    u16x8 o;
    o[0] = f2bf(v0.x); o[1] = f2bf(v0.y); o[2] = f2bf(v0.z); o[3] = f2bf(v0.w);
    o[4] = f2bf(v1.x); o[5] = f2bf(v1.y); o[6] = f2bf(v1.z); o[7] = f2bf(v1.w);
    *(u16x8*)(xbf + i * 8) = o;
  }
}

// ---------------- convert [W_alpha;W_beta;W_x] -> bf16 hi/lo split ----------------
__global__ __launch_bounds__(256) void convert_w_kernel(const float* __restrict__ Wa,
                                                        const float* __restrict__ Wb,
                                                        const float* __restrict__ Wx,
                                                        unsigned short* __restrict__ whi,
                                                        unsigned short* __restrict__ wlo) {
  const long n4 = (3l * 1024 * 1024) / 4;
  const long stride = (long)gridDim.x * blockDim.x;
  for (long i = (long)blockIdx.x * blockDim.x + threadIdx.x; i < n4; i += stride) {
    long e = i * 4;
    int mat = (int)(e >> 20);
    long off = e & 1048575l;
    const float* src = (mat == 0) ? Wa : (mat == 1) ? Wb : Wx;
    float4 v = *(const float4*)(src + off);
    u16x4 hi, lo;
    hi[0] = f2bf(v.x); lo[0] = f2bf(v.x - bf2f(hi[0]));
    hi[1] = f2bf(v.y); lo[1] = f2bf(v.y - bf2f(hi[1]));
    hi[2] = f2bf(v.z); lo[2] = f2bf(v.z - bf2f(hi[2]));
    hi[3] = f2bf(v.w); lo[3] = f2bf(v.w - bf2f(hi[3]));
    *(u16x4*)(whi + e) = hi;
    *(u16x4*)(wlo + e) = lo;
  }
}

// ---------------- fused pre-GEMM: alpha/beta/wx = act(x @ Wcat^T + bias) ----------------
// C[r][n'] = sum_k xbf[r][k] * (Whi[n'][k] + Wlo[n'][k]);  n' in [0,3072)
// region 0 -> sigmoid(+b_alpha) -> alpha (stored into h region offset BD of d_out)
// region 1 -> sigmoid(+b_beta)  -> beta  (stored into out region of d_out)
// region 2 -> +b                -> wx    (stored into ws)
__global__ __launch_bounds__(256) void gemm_pre(
    const unsigned short* __restrict__ xbf,
    const unsigned short* __restrict__ whi,
    const unsigned short* __restrict__ wlo,
    const float* __restrict__ b_alpha, const float* __restrict__ b_beta, const float* __restrict__ b_x,
    float* __restrict__ alpha_dst, float* __restrict__ beta_dst, float* __restrict__ wx_dst)
{
  __shared__ unsigned short Al[128 * 64];
  __shared__ unsigned short Bh[128 * 64];
  __shared__ unsigned short Bl[128 * 64];
  const int tid  = threadIdx.x;
  const int lane = tid & 63;
  const int w    = tid >> 6;
  const int wm   = w >> 1, wn = w & 1;
  const long rowA0 = (long)blockIdx.x * 128;
  const int  colB0 = blockIdx.y * 128;

  f32x4 acc[4][4];
#pragma unroll
  for (int i = 0; i < 4; ++i)
#pragma unroll
    for (int j = 0; j < 4; ++j) acc[i][j] = (f32x4){0.f, 0.f, 0.f, 0.f};

  for (int k0 = 0; k0 < 1024; k0 += 64) {
#pragma unroll
    for (int is = 0; is < 4; ++is) {
      const int o   = is * 4096 + tid * 16;   // byte offset within 16KB tile
      const int row = o >> 7;                 // 128B per row
      const int ke  = (o & 127) >> 1;         // element within row
      const long asrc = (rowA0 + row) * 1024 + (k0 + ke);
      const long bsrc = ((long)(colB0 + row)) * 1024 + (k0 + ke);
      gload_lds16(xbf + asrc, (char*)Al + is * 4096 + w * 1024);
      gload_lds16(whi + bsrc, (char*)Bh + is * 4096 + w * 1024);
      gload_lds16(wlo + bsrc, (char*)Bl + is * 4096 + w * 1024);
    }
    asm volatile("s_waitcnt vmcnt(0)" ::: "memory");
    __syncthreads();
#pragma unroll
    for (int kk = 0; kk < 2; ++kk) {
      const int koff = kk * 64 + ((lane >> 4) * 16);   // byte offset in row
      s16x8 a[4], bhf[4], blf[4];
#pragma unroll
      for (int i = 0; i < 4; ++i)
        a[i] = *(const s16x8*)((const char*)Al + (wm * 64 + i * 16 + (lane & 15)) * 128 + koff);
#pragma unroll
      for (int j = 0; j < 4; ++j) {
        const int r = (wn * 64 + j * 16 + (lane & 15)) * 128 + koff;
        bhf[j] = *(const s16x8*)((const char*)Bh + r);
        blf[j] = *(const s16x8*)((const char*)Bl + r);
      }
#pragma unroll
      for (int i = 0; i < 4; ++i)
#pragma unroll
        for (int j = 0; j < 4; ++j) {
          acc[i][j] = __builtin_amdgcn_mfma_f32_16x16x32_bf16(a[i], bhf[j], acc[i][j], 0, 0, 0);
          acc[i][j] = __builtin_amdgcn_mfma_f32_16x16x32_bf16(a[i], blf[j], acc[i][j], 0, 0, 0);
        }
    }
    __syncthreads();
  }

  const int region = colB0 >> 10;   // uniform per block
  const float* bias = (region == 0) ? b_alpha : (region == 1) ? b_beta : b_x;
  float* dst = (region == 0) ? alpha_dst : (region == 1) ? beta_dst : wx_dst;
#pragma unroll
  for (int j = 0; j < 4; ++j) {
    const int colg = colB0 + wn * 64 + j * 16 + (lane & 15);
    const int nl = colg & 1023;
    const float bj = bias[nl];
#pragma unroll
    for (int i = 0; i < 4; ++i) {
#pragma unroll
      for (int r = 0; r < 4; ++r) {
        const long rowg = rowA0 + wm * 64 + i * 16 + ((lane >> 4) * 4) + r;
        float z = acc[i][j][r] + bj;
        float val = (region == 2) ? z : (1.0f / (1.0f + __expf(-z)));
        dst[rowg * 1024 + nl] = val;
      }
    }
  }
}

// ---------------- persistent scan kernel ----------------
// 64 WGs x 256 threads. WG wg owns output channels [wg*16, wg*16+16).
// W_h slice cached in LDS as bf16 hi/lo (3-term split MFMA => ~fp32 accuracy).
// h communicated across WGs via agent-scope atomics in ping-pong hi/lo bf16 planes,
// laid out so MFMA A-fragments are loaded directly (16B per lane).
static __device__ __forceinline__ void publish_h(unsigned short* __restrict__ bhi,
                                                 unsigned short* __restrict__ blo,
                                                 int buf, int b, int n, float hn, int tid) {
  unsigned short hi = f2bf(hn);
  unsigned short lo = f2bf(hn - bf2f(hi));
  int hv = hi, lv = lo;
  int hn2 = __shfl_xor(hv, 1);
  int ln2 = __shfl_xor(lv, 1);
  if (!(tid & 1)) {   // even thread stores packed {n, n+1}
    unsigned ph = (unsigned)hv | ((unsigned)hn2 << 16);
    unsigned pl = (unsigned)lv | ((unsigned)ln2 << 16);
    long base = (long)buf * BD + (long)b * DIM + n;   // n even -> 4B aligned
    __hip_atomic_store((unsigned*)(bhi + base), ph, __ATOMIC_RELAXED, __HIP_MEMORY_SCOPE_AGENT);
    __hip_atomic_store((unsigned*)(blo + base), pl, __ATOMIC_RELAXED, __HIP_MEMORY_SCOPE_AGENT);
  }
}

static __device__ __forceinline__ void spin_wait(int* __restrict__ flags, int tgt, int w, int lane) {
  if (w == 0) {
    int iters = 0;
    while (true) {
      int f = __hip_atomic_load(&flags[lane], __ATOMIC_RELAXED, __HIP_MEMORY_SCOPE_AGENT);
      if (__all(f >= tgt)) break;
      __builtin_amdgcn_s_sleep(2);
      if (++iters > (1 << 24)) break;   // safety valve: wrong answer beats a hang
    }
  }
}

__global__ __launch_bounds__(256) void scan_kernel(
    const float* __restrict__ Wh,
    const float* __restrict__ h0,
    const float* __restrict__ wxb,
    float* __restrict__ out_buf,     // d_out: out region; beta pre-stored here
    float* __restrict__ h_out,       // d_out + OUT_ELEMS: h region; alpha pre-stored at +BD
    unsigned short* __restrict__ hbh,
    unsigned short* __restrict__ hbl,
    int* __restrict__ flags)
{
  const int tid  = threadIdx.x;
  const int lane = tid & 63;
  const int w    = tid >> 6;
  const int wg   = blockIdx.x;
  const int n0   = wg * 16;

  __shared__ unsigned short WhiL[16 * 1024];
  __shared__ unsigned short WloL[16 * 1024];
  __shared__ float zred[4][256];

  // ---- stage W_h slice into LDS (hi/lo, XOR-swizzled for conflict-free b128 reads) ----
  {
    const int row = tid >> 4;            // 0..15 (channel within slice)
    const int kb  = (tid & 15) * 64;     // k base
    const float* src = Wh + (size_t)(n0 + row) * 1024 + kb;
    const unsigned sx = ((unsigned)(row & 7)) << 4;
    const unsigned rb = (unsigned)row * 2048u;
#pragma unroll
    for (int q = 0; q < 16; ++q) {
      float4 v = *(const float4*)(src + q * 4);
      u16x4 hi, lo;
      hi[0] = f2bf(v.x); lo[0] = f2bf(v.x - bf2f(hi[0]));
      hi[1] = f2bf(v.y); lo[1] = f2bf(v.y - bf2f(hi[1]));
      hi[2] = f2bf(v.z); lo[2] = f2bf(v.z - bf2f(hi[2]));
      hi[3] = f2bf(v.w); lo[3] = f2bf(v.w - bf2f(hi[3]));
      const unsigned addr = (rb + (unsigned)(kb + q * 4) * 2u) ^ sx;
      *(u16x4*)((char*)WhiL + addr) = hi;
      *(u16x4*)((char*)WloL + addr) = lo;
    }
  }

  const int b_own  = tid >> 4;
  const int nl_own = tid & 15;
  const long off_own = (long)b_own * 1024 + n0 + nl_own;

  // ---- phase 0: h[0] = h0 ----
  float hprev = h0[off_own];
  h_out[off_own] = hprev;
  publish_h(hbh, hbl, 0, b_own, n0 + nl_own, hprev, tid);
  __syncthreads();
  if (tid == 0) __hip_atomic_store(&flags[wg], 1, __ATOMIC_RELEASE, __HIP_MEMORY_SCOPE_AGENT);
  spin_wait(flags, 1, w, lane);
  __syncthreads();

  // triple for t=0 (alpha lives at h[t+1] slot, beta at out[t] slot — same-thread overlap trick)
  float alpha_c = h_out[BD + off_own];
  float beta_c  = out_buf[off_own];
  float wx_c    = wxb[off_own];

  const int arow = lane & 15;                      // A row (=batch) and B col (=channel)
  const int kq   = w * 256 + ((lane >> 4) * 8);    // this wave's K-quarter base for this lane
  const unsigned bswz = ((unsigned)(arow & 7)) << 4;
  const unsigned brow = (unsigned)arow * 2048u;

  for (int t = 0; t < T_STEPS; ++t) {
    const unsigned short* cur_hi = hbh + (size_t)(t & 1) * BD;
    const unsigned short* cur_lo = hbl + (size_t)(t & 1) * BD;

    // prefetch next step's alpha/beta/wx (consumed next iteration)
    float a_n = 0.f, b_n = 0.f, w_n = 0.f;
    if (t + 1 < T_STEPS) {
      const long o = (long)(t + 1) * BD + off_own;
      a_n = h_out[BD + o];
      b_n = out_buf[o];
      w_n = wxb[o];
    }

    // ---- z = h_prev @ Wh_slice^T  (3-term bf16 split MFMA, K split across 4 waves) ----
    f32x4 acc0 = (f32x4){0.f,0.f,0.f,0.f};
    f32x4 acc1 = (f32x4){0.f,0.f,0.f,0.f};
    f32x4 acc2 = (f32x4){0.f,0.f,0.f,0.f};
    union AB { unsigned long long u[2]; s16x8 v; };
    s16x8 ahi[8], alo8[8];
#pragma unroll
    for (int s = 0; s < 8; ++s) {
      const int ko = kq + s * 32;
      const unsigned long long* ph = (const unsigned long long*)(cur_hi + (arow << 10) + ko);
      const unsigned long long* pl = (const unsigned long long*)(cur_lo + (arow << 10) + ko);
      AB th, tl;
      th.u[0] = __hip_atomic_load(ph,     __ATOMIC_RELAXED, __HIP_MEMORY_SCOPE_AGENT);
      th.u[1] = __hip_atomic_load(ph + 1, __ATOMIC_RELAXED, __HIP_MEMORY_SCOPE_AGENT);
      tl.u[0] = __hip_atomic_load(pl,     __ATOMIC_RELAXED, __HIP_MEMORY_SCOPE_AGENT);
      tl.u[1] = __hip_atomic_load(pl + 1, __ATOMIC_RELAXED, __HIP_MEMORY_SCOPE_AGENT);
      ahi[s] = th.v; alo8[s] = tl.v;
    }
#pragma unroll
    for (int s = 0; s < 8; ++s) {
      const int ko = kq + s * 32;
      const unsigned baddr = (brow + (unsigned)ko * 2u) ^ bswz;
      s16x8 bh = *(const s16x8*)((const char*)WhiL + baddr);
      s16x8 bl = *(const s16x8*)((const char*)WloL + baddr);
      acc0 = __builtin_amdgcn_mfma_f32_16x16x32_bf16(ahi[s],  bh, acc0, 0, 0, 0);
      acc1 = __builtin_amdgcn_mfma_f32_16x16x32_bf16(ahi[s],  bl, acc1, 0, 0, 0);
      acc2 = __builtin_amdgcn_mfma_f32_16x16x32_bf16(alo8[s], bh, acc2, 0, 0, 0);
    }
    f32x4 zp = acc0 + acc1 + acc2;
#pragma unroll
    for (int r = 0; r < 4; ++r) {
      const int bidx = (lane >> 4) * 4 + r;          // batch index of this C element
      zred[w][bidx * 16 + arow] = zp[r];
    }
    __syncthreads();

    // ---- elementwise update (thread owns (b_own, n0+nl_own)) ----
    const float z  = zred[0][tid] + zred[1][tid] + zred[2][tid] + zred[3][tid] + wx_c;
    const float v  = tanhf(z);
    const float hn = alpha_c * hprev + beta_c * v;
    const long o = (long)t * BD + off_own;
    h_out[BD + o] = hn;                              // h[t+1] (overwrites alpha[t] slot)
    const float sg = 1.0f / (1.0f + __expf(-hn));
    out_buf[o] = hn * hn * sg;                       // out[t] = hn*silu(hn) (overwrites beta[t])
    publish_h(hbh, hbl, (t + 1) & 1, b_own, n0 + nl_own, hn, tid);
    hprev = hn;
    alpha_c = a_n; beta_c = b_n; wx_c = w_n;

    __syncthreads();   // drains all waves' stores (vmcnt(0) before s_barrier)
    if (tid == 0) __hip_atomic_store(&flags[wg], t + 2, __ATOMIC_RELEASE, __HIP_MEMORY_SCOPE_AGENT);
    spin_wait(flags, t + 2, w, lane);
    __syncthreads();
  }
}

// ---------------- launch ----------------
extern "C" void kernel_launch(void* const* d_in, const int* in_sizes, int n_in,
                              void* d_out, int out_size, void* d_ws, size_t ws_size,
                              hipStream_t stream) {
  const float* x  = (const float*)d_in[0];
  const float* h0 = (const float*)d_in[1];
  const float* Wa = (const float*)d_in[2];
  const float* ba = (const float*)d_in[3];
  const float* Wb = (const float*)d_in[4];
  const float* bb = (const float*)d_in[5];
  const float* Wh = (const float*)d_in[6];
  const float* Wx = (const float*)d_in[7];
  const float* bx = (const float*)d_in[8];

  float* out_buf = (float*)d_out;
  float* h_out   = out_buf + OUT_ELEMS;

  char* ws = (char*)d_ws;
  float*          wx_buf = (float*)(ws + WX_OFF);
  unsigned short* xbf    = (unsigned short*)(ws + XBF_OFF);
  unsigned short* whi    = (unsigned short*)(ws + WHI_OFF);
  unsigned short* wlo    = (unsigned short*)(ws + WLO_OFF);
  unsigned short* hbh    = (unsigned short*)(ws + HBH_OFF);
  unsigned short* hbl    = (unsigned short*)(ws + HBL_OFF);
  int*            flags  = (int*)(ws + FLG_OFF);

  hipMemsetAsync(flags, 0, 256, stream);
  convert_x_kernel<<<4096, 256, 0, stream>>>(x, xbf);
  convert_w_kernel<<<1024, 256, 0, stream>>>(Wa, Wb, Wx, whi, wlo);
  // alpha -> h region at +BD (h[t+1] slots); beta -> out region (out[t] slots); wx -> ws
  gemm_pre<<<dim3(256, 24), 256, 0, stream>>>(xbf, whi, wlo, ba, bb, bx,
                                              h_out + BD, out_buf, wx_buf);
  scan_kernel<<<64, 256, 0, stream>>>(Wh, h0, wx_buf, out_buf, h_out, hbh, hbl, flags);
}